// Round 8
// baseline (3633.526 us; speedup 1.0000x reference)
//
#include <hip/hip_runtime.h>

// OSQP batched ADMM, B=256 N=128 M=192, 400 iters.
// R8: loop kernel at 512 threads/block. Root cause of R6/R7 spill: backend
// derives VGPR budget from LDS-fit occupancy -> with 1024-thr blocks + 54KiB
// LDS, 2 WGs fit in 160KiB -> 8 waves/EU target -> 64-VGPR budget -> scratch
// spill in the 400-iter loop (1-1.6 GB/dispatch HBM churn). At 512 thr the
// same LDS gives 4 waves/EU -> 128 VGPRs -> Vr[6][12]=72 accs fit, no spill.
// Side benefits: rows/thread 3->6 halves loop LDS traffic (49->24.5 KB/iter)
// and halves DPP-per-FMA overhead.
// Precompute: R6 version verbatim (~135us measured).
// Algebra: M = P + sI + rho*AtA (SPD);  Wt = A*Minv;  c = Minv q
//   V = A Minv At;  d = A c
//   iterate (s_0=0), state (p = (1-a)z + y/rho, s, Sacc):
//     r = V s ; w = r - d ; v = a*w + p ; z = med3(v,l,u) ;
//     s' = rho*(2z - v) ; Sacc' = (1-a)Sacc + a*s ; p' = v - a*z
//   epilogue: x = Wt^T Sacc - c

#define Nn 128
#define Mm 192
constexpr float RHO_    = 0.1f;
constexpr float SIGMA_  = 1e-6f;
constexpr float ALPHA_  = 1.6f;
constexpr int   NITERS_ = 400;

typedef float v4f __attribute__((ext_vector_type(4)));

template<int CTRL>
__device__ __forceinline__ float dpp_add(float x) {
  int y = __builtin_amdgcn_update_dpp(__float_as_int(x), __float_as_int(x),
                                      CTRL, 0xF, 0xF, false);
  return x + __int_as_float(y);
}
__device__ __forceinline__ float red16(float x) {
  x = dpp_add<0x121>(x); x = dpp_add<0x122>(x);
  x = dpp_add<0x124>(x); x = dpp_add<0x128>(x);
  return x;
}

//======================= Kernel 1: precompute Wt, c (1024 thr) =====================
// [R6-validated, unchanged]
template<int K0>
__device__ __forceinline__ void gj_block8(float rr[16], float* __restrict__ buf0,
                                          float* __restrict__ buf1,
                                          const int irow, const int oct) {
  #pragma unroll
  for (int kk = 0; kk < 16; kk++) {
    const int k = 16*K0 + kk;
    float* wb = ((kk & 1) == 0) ? buf0 : buf1;
    if (irow == k) {                    // 8 lanes store unnormalized pivot row
      #pragma unroll
      for (int j4 = 0; j4 < 4; j4++)
        *(float4*)&wb[20*oct + 4*j4] = *(const float4*)&rr[4*j4];
    }
    __syncthreads();
    const float akk = wb[20*K0 + kk];            // wave-uniform broadcast
    float pinv = __builtin_amdgcn_rcpf(akk);
    pinv = pinv + pinv*(1.0f - akk*pinv);        // 1 Newton step
    const int fi = __builtin_amdgcn_ds_swizzle(__float_as_int(rr[kk]),
                                               (K0 << 5) | 0x18);
    const float f = __int_as_float(fi);
    const bool piv = (irow == k);
    const float gfac = piv ? (1.0f - pinv) : (f * pinv);
    float rk[16];
    #pragma unroll
    for (int j4 = 0; j4 < 4; j4++)
      *(float4*)&rk[4*j4] = *(const float4*)&wb[20*oct + 4*j4];
    #pragma unroll
    for (int j = 0; j < 16; j++) rr[j] -= gfac * rk[j];
    if (oct == K0) rr[kk] = piv ? pinv : -gfac;  // in-place inverse column
  }
}

__global__ void __launch_bounds__(1024, 4)
precompute_kernel(const float* __restrict__ Pg, const float* __restrict__ qg,
                  const float* __restrict__ Ag, float* __restrict__ wsWt,
                  float* __restrict__ wsC)
{
  __shared__ float smem[16384];   // 64 KiB, aliased across phases
  const int t = threadIdx.x;
  const int b = blockIdx.x;
  const float* __restrict__ Pb = Pg + (size_t)b*Nn*Nn;
  const float* __restrict__ qb = qg + (size_t)b*Nn;
  const float* __restrict__ Ab = Ag + (size_t)b*Mm*Nn;

  //---- Phase A: S = P + sigma*I + rho*AtA; 4x4 tile per thread ----
  {
    const int ar = t & 31;              // rows 4ar..4ar+4
    const int bc = t >> 5;              // cols 4bc..4bc+4
    float acc[4][4];
    #pragma unroll
    for (int a=0;a<4;a++)
      #pragma unroll
      for (int v=0;v<4;v++) acc[a][v]=0.f;

    for (int c=0;c<6;c++) {
      __syncthreads();
      { // stage A rows [32c,32c+32) x 128: 4096 floats, 1 float4/thread
        ((float4*)smem)[t] = ((const float4*)(Ab + c*32*Nn))[t];
      }
      __syncthreads();
      #pragma unroll 4
      for (int m=0;m<32;m++) {
        const float4 ri = *(const float4*)&smem[m*Nn + 4*ar];
        const float4 rj = *(const float4*)&smem[m*Nn + 4*bc];
        const float iv[4] = {ri.x,ri.y,ri.z,ri.w};
        const float jv[4] = {rj.x,rj.y,rj.z,rj.w};
        #pragma unroll
        for (int a=0;a<4;a++)
          #pragma unroll
          for (int v=0;v<4;v++) acc[a][v] += iv[a]*jv[v];
      }
    }
    __syncthreads();
    #pragma unroll
    for (int a=0;a<4;a++) {
      const int i = 4*ar + a;
      const float4 p = *(const float4*)&Pb[i*Nn + 4*bc];
      float4 o;
      o.x = p.x + RHO_*acc[a][0] + ((i==4*bc+0)?SIGMA_:0.f);
      o.y = p.y + RHO_*acc[a][1] + ((i==4*bc+1)?SIGMA_:0.f);
      o.z = p.z + RHO_*acc[a][2] + ((i==4*bc+2)?SIGMA_:0.f);
      o.w = p.w + RHO_*acc[a][3] + ((i==4*bc+3)?SIGMA_:0.f);
      *(float4*)&smem[i*Nn + 4*bc] = o;
    }
    __syncthreads();
  }

  //---- Phase B: S <- S^-1 Gauss-Jordan, 8 lanes/row, 1 barrier/step ----
  {
    const int irow = t >> 3;            // 0..127
    const int oct  = t & 7;             // col 16-chunk
    float rr[16];
    #pragma unroll
    for (int j4=0;j4<4;j4++)
      *(float4*)&rr[4*j4] = *(const float4*)&smem[irow*Nn + 16*oct + 4*j4];
    __syncthreads();                    // all rr loaded before bufs alias smem
    float* buf0 = smem;                 // [160]
    float* buf1 = smem + 160;           // [160]
    gj_block8<0>(rr, buf0, buf1, irow, oct);
    gj_block8<1>(rr, buf0, buf1, irow, oct);
    gj_block8<2>(rr, buf0, buf1, irow, oct);
    gj_block8<3>(rr, buf0, buf1, irow, oct);
    gj_block8<4>(rr, buf0, buf1, irow, oct);
    gj_block8<5>(rr, buf0, buf1, irow, oct);
    gj_block8<6>(rr, buf0, buf1, irow, oct);
    gj_block8<7>(rr, buf0, buf1, irow, oct);
    __syncthreads();                    // last step's reads done
    #pragma unroll
    for (int j4=0;j4<4;j4++)
      *(float4*)&smem[irow*Nn + 16*oct + 4*j4] = *(const float4*)&rr[4*j4];
  }
  __syncthreads();

  //---- Phase C: Wt = A*Minv -> wsWt; c = Minv q -> wsC ----
  {
    const int rg = t >> 4, cg = t & 15;
    float acc[3][8];
    #pragma unroll
    for (int a=0;a<3;a++)
      #pragma unroll
      for (int p=0;p<8;p++) acc[a][p]=0.f;

    for (int k4=0;k4<32;k4++) {
      v4f av[3];
      av[0] = *(const v4f*)&Ab[(rg      )*Nn + 4*k4];
      av[1] = *(const v4f*)&Ab[(rg +  64)*Nn + 4*k4];
      av[2] = *(const v4f*)&Ab[(rg + 128)*Nn + 4*k4];
      #pragma unroll
      for (int q=0;q<4;q++) {
        const int m = 4*k4 + q;
        const v4f w0 = *(const v4f*)&smem[m*Nn + 8*cg];
        const v4f w1 = *(const v4f*)&smem[m*Nn + 8*cg + 4];
        #pragma unroll
        for (int a=0;a<3;a++) {
          const float amq = (q==0)?av[a].x : (q==1)?av[a].y : (q==2)?av[a].z : av[a].w;
          acc[a][0] += amq*w0.x; acc[a][1] += amq*w0.y;
          acc[a][2] += amq*w0.z; acc[a][3] += amq*w0.w;
          acc[a][4] += amq*w1.x; acc[a][5] += amq*w1.y;
          acc[a][6] += amq*w1.z; acc[a][7] += amq*w1.w;
        }
      }
    }
    float* wb = wsWt + (size_t)b*Mm*Nn;
    #pragma unroll
    for (int a=0;a<3;a++) {
      const int j = rg + 64*a;
      *(float4*)&wb[j*Nn + 8*cg]     = make_float4(acc[a][0],acc[a][1],acc[a][2],acc[a][3]);
      *(float4*)&wb[j*Nn + 8*cg + 4] = make_float4(acc[a][4],acc[a][5],acc[a][6],acc[a][7]);
    }
  }
  // c[r] = sum_k Minv[k][r] q[k]  (Minv symmetric; lane-consecutive LDS reads)
  if (t < Nn) {
    float cc = 0.f;
    #pragma unroll 4
    for (int k=0;k<Nn;k++) cc += smem[k*Nn + t] * qb[k];
    wsC[(size_t)b*Nn + t] = cc;
  }
}

//======================= Kernel 2: V-space ADMM loop (512 thr) =====================
// wg = t>>4 (0..31), cg = t&15. Thread owns V rows {wg+32a : a<6} x cols
// {16jj+cg : jj<12} (s stored transposed: s_j at slot (j&15)*12 + (j>>4), so
// lane cg reads 12 contiguous floats = cols j with j&15==cg). Producers:
// cg<6, row pm = 32*cg + wg.
#define ABASE 0
#define WBASE 6912
__global__ void __launch_bounds__(512, 4)
loop_kernel(const float* __restrict__ Ag, const float* __restrict__ lg,
            const float* __restrict__ ug, const float* __restrict__ wsWt,
            const float* __restrict__ wsC, float* __restrict__ outg)
{
  __shared__ float smem[13824];   // 54 KiB: A-tile[192][36] + Wt-tile[192][36]
  const int t = threadIdx.x, b = blockIdx.x;
  const int wg = t >> 4, cg = t & 15;
  const float* __restrict__ Ab = Ag   + (size_t)b*Mm*Nn;
  const float* __restrict__ Wb = wsWt + (size_t)b*Mm*Nn;
  const float* __restrict__ cb = wsC  + (size_t)b*Nn;

  const int  pm  = 32*cg + wg;          // producer row (cg<6)
  const bool isp = (cg < 6);

  // ---- d = A_pm . c ; bounds (producers) ----
  float dreg = 0.f, lreg = 0.f, ureg = 0.f;
  if (isp) {
    lreg = lg[(size_t)b*Mm + pm];
    ureg = ug[(size_t)b*Mm + pm];
    const float4* ar = (const float4*)(Ab + pm*Nn);
    const float4* cr = (const float4*)cb;
    #pragma unroll 4
    for (int k4=0;k4<32;k4++) {
      const float4 av = ar[k4], cv = cr[k4];
      dreg += av.x*cv.x + av.y*cv.y + av.z*cv.z + av.w*cv.w;
    }
  }

  // ---- prologue: V rows into regs.  Vr[a][jj] = dot(A_{wg+32a}, Wt_{cg+16jj}) ----
  float Vr[6][12];
  #pragma unroll
  for (int a=0;a<6;a++)
    #pragma unroll
    for (int jj=0;jj<12;jj++) Vr[a][jj] = 0.f;

  for (int kc=0; kc<4; kc++) {
    __syncthreads();
    { // stage A[0:192][32kc:+32] and Wt[0:192][32kc:+32], padded stride 36
      #pragma unroll
      for (int i=0;i<3;i++) {
        const int x = t + 512*i;
        const int row = x>>3, c4 = x&7;
        *(float4*)&smem[ABASE + 36*row + 4*c4] = *(const float4*)&Ab[row*Nn + 32*kc + 4*c4];
        *(float4*)&smem[WBASE + 36*row + 4*c4] = *(const float4*)&Wb[row*Nn + 32*kc + 4*c4];
      }
    }
    __syncthreads();
    #pragma unroll
    for (int m4=0; m4<8; m4++) {
      v4f av[6];
      #pragma unroll
      for (int a=0;a<6;a++)
        av[a] = *(const v4f*)&smem[ABASE + 36*(wg + 32*a) + 4*m4];
      #pragma unroll
      for (int jj=0; jj<12; jj++) {
        const v4f w = *(const v4f*)&smem[WBASE + 36*(cg + 16*jj) + 4*m4];
        #pragma unroll
        for (int a=0;a<6;a++)
          Vr[a][jj] += av[a].x*w.x + av[a].y*w.y + av[a].z*w.z + av[a].w*w.w;
      }
    }
  }

  __syncthreads();
  float* sT0  = smem;
  float* sT1  = smem + 192;
  float* sacc = smem + 384;
  if (t < Mm) sT0[t] = 0.f;
  __syncthreads();

  const int woff = (pm & 15)*12 + (pm >> 4);
  // state: p = (1-a)z + y/rho (0 at start), s, Sacc
  float sreg = 0.f, preg = 0.f, Sacc = 0.f;
  const float* sR0 = sT0 + 12*cg;
  const float* sR1 = sT1 + 12*cg;

#define ITER(RD, WR)                                                           \
  {                                                                            \
    const float4 sA = *(const float4*)(RD);                                    \
    const float4 sB = *(const float4*)((RD) + 4);                              \
    const float4 sC = *(const float4*)((RD) + 8);                              \
    float rr[6];                                                               \
    _Pragma("unroll")                                                          \
    for (int a=0;a<6;a++) {                                                    \
      rr[a] = Vr[a][0]*sA.x + Vr[a][1]*sA.y + Vr[a][2]*sA.z + Vr[a][3]*sA.w    \
            + Vr[a][4]*sB.x + Vr[a][5]*sB.y + Vr[a][6]*sB.z + Vr[a][7]*sB.w    \
            + Vr[a][8]*sC.x + Vr[a][9]*sC.y + Vr[a][10]*sC.z + Vr[a][11]*sC.w; \
      rr[a] = red16(rr[a]);                                                    \
    }                                                                          \
    if (isp) {                                                                 \
      const float r  = (cg==0) ? rr[0] : (cg==1) ? rr[1] : (cg==2) ? rr[2]     \
                     : (cg==3) ? rr[3] : (cg==4) ? rr[4] : rr[5];              \
      const float w  = r - dreg;                                               \
      const float v  = fmaf(ALPHA_, w, preg);                                  \
      const float z  = __builtin_amdgcn_fmed3f(v, lreg, ureg);                 \
      const float sn = RHO_ * fmaf(2.0f, z, -v);                               \
      (WR)[woff] = sn;                                                         \
      Sacc = (1.f-ALPHA_)*Sacc + ALPHA_*sreg;                                  \
      sreg = sn;                                                               \
      preg = fmaf(-ALPHA_, z, v);                                              \
    }                                                                          \
    __syncthreads();                                                           \
  }

  #pragma unroll 1
  for (int it2 = 0; it2 < NITERS_/2; it2++) {
    ITER(sR0, sT1)
    ITER(sR1, sT0)
  }
#undef ITER

  // ---- epilogue: x = Wt^T Sacc - c ----
  if (isp) sacc[pm] = Sacc;
  __syncthreads();
  if (t < Nn) {
    float acc = -cb[t];
    #pragma unroll 4
    for (int j=0;j<Mm;j++) acc += Wb[j*Nn + t] * sacc[j];
    outg[(size_t)b*Nn + t] = acc;
  }
}

extern "C" void kernel_launch(void* const* d_in, const int* in_sizes, int n_in,
                              void* d_out, int out_size, void* d_ws, size_t ws_size,
                              hipStream_t stream) {
  const float* P = (const float*)d_in[0];
  const float* q = (const float*)d_in[1];
  const float* A = (const float*)d_in[2];
  const float* l = (const float*)d_in[3];
  const float* u = (const float*)d_in[4];
  (void)in_sizes; (void)n_in; (void)out_size; (void)ws_size;
  float* wsWt = (float*)d_ws;                      // 256*192*128 floats = 25.2 MB
  float* wsC  = wsWt + (size_t)256*Mm*Nn;          // 256*128 floats
  precompute_kernel<<<256, 1024, 0, stream>>>(P, q, A, wsWt, wsC);
  loop_kernel<<<256, 512, 0, stream>>>(A, l, u, wsWt, wsC, (float*)d_out);
}

// Round 9
// 513.625 us; speedup vs baseline: 7.0743x; 7.0743x over previous
//
#include <hip/hip_runtime.h>

// OSQP batched ADMM, B=256 N=128 M=192, 400 iters. Three kernels.
// R9: design within the 64-VGPR budget (R1-R8 evidence: allocator pins 64
// regs for min_waves=4 regardless of block size/LDS/attributes; spill of the
// V rows caused R6-R8 regressions). V is now computed by a dedicated GEMM
// kernel into per-loop-thread contiguous 144B blobs in d_ws; the loop kernel
// has no tile prologue (9 coalesced float4 loads, 2.3KB LDS, ~55 live regs).
// Algebra: M = P + sI + rho*AtA (SPD);  Wt = A*Minv;  c = Minv q
//   V = A Minv At = Wt . A^T;  d = A c
//   iterate (s_0=0), state (p = (1-a)z + y/rho, s, Sacc):
//     r = V s ; w = r - d ; v = a*w + p ; z = med3(v,l,u) ;
//     s' = rho*(2z - v) ; Sacc' = (1-a)Sacc + a*s ; p' = v - a*z
//   epilogue: x = Wt^T Sacc - c

#define Nn 128
#define Mm 192
constexpr float RHO_    = 0.1f;
constexpr float SIGMA_  = 1e-6f;
constexpr float ALPHA_  = 1.6f;
constexpr int   NITERS_ = 400;

typedef float v4f __attribute__((ext_vector_type(4)));

template<int CTRL>
__device__ __forceinline__ float dpp_add(float x) {
  int y = __builtin_amdgcn_update_dpp(__float_as_int(x), __float_as_int(x),
                                      CTRL, 0xF, 0xF, false);
  return x + __int_as_float(y);
}
__device__ __forceinline__ float red16(float x) {
  x = dpp_add<0x121>(x); x = dpp_add<0x122>(x);
  x = dpp_add<0x124>(x); x = dpp_add<0x128>(x);
  return x;
}

//======================= Kernel 1: precompute Wt, c (1024 thr) =====================
// [R6-validated, unchanged]
template<int K0>
__device__ __forceinline__ void gj_block8(float rr[16], float* __restrict__ buf0,
                                          float* __restrict__ buf1,
                                          const int irow, const int oct) {
  #pragma unroll
  for (int kk = 0; kk < 16; kk++) {
    const int k = 16*K0 + kk;
    float* wb = ((kk & 1) == 0) ? buf0 : buf1;
    if (irow == k) {                    // 8 lanes store unnormalized pivot row
      #pragma unroll
      for (int j4 = 0; j4 < 4; j4++)
        *(float4*)&wb[20*oct + 4*j4] = *(const float4*)&rr[4*j4];
    }
    __syncthreads();
    const float akk = wb[20*K0 + kk];            // wave-uniform broadcast
    float pinv = __builtin_amdgcn_rcpf(akk);
    pinv = pinv + pinv*(1.0f - akk*pinv);        // 1 Newton step
    const int fi = __builtin_amdgcn_ds_swizzle(__float_as_int(rr[kk]),
                                               (K0 << 5) | 0x18);
    const float f = __int_as_float(fi);
    const bool piv = (irow == k);
    const float gfac = piv ? (1.0f - pinv) : (f * pinv);
    float rk[16];
    #pragma unroll
    for (int j4 = 0; j4 < 4; j4++)
      *(float4*)&rk[4*j4] = *(const float4*)&wb[20*oct + 4*j4];
    #pragma unroll
    for (int j = 0; j < 16; j++) rr[j] -= gfac * rk[j];
    if (oct == K0) rr[kk] = piv ? pinv : -gfac;  // in-place inverse column
  }
}

__global__ void __launch_bounds__(1024, 4)
precompute_kernel(const float* __restrict__ Pg, const float* __restrict__ qg,
                  const float* __restrict__ Ag, float* __restrict__ wsWt,
                  float* __restrict__ wsC)
{
  __shared__ float smem[16384];   // 64 KiB, aliased across phases
  const int t = threadIdx.x;
  const int b = blockIdx.x;
  const float* __restrict__ Pb = Pg + (size_t)b*Nn*Nn;
  const float* __restrict__ qb = qg + (size_t)b*Nn;
  const float* __restrict__ Ab = Ag + (size_t)b*Mm*Nn;

  //---- Phase A: S = P + sigma*I + rho*AtA; 4x4 tile per thread ----
  {
    const int ar = t & 31;              // rows 4ar..4ar+4
    const int bc = t >> 5;              // cols 4bc..4bc+4
    float acc[4][4];
    #pragma unroll
    for (int a=0;a<4;a++)
      #pragma unroll
      for (int v=0;v<4;v++) acc[a][v]=0.f;

    for (int c=0;c<6;c++) {
      __syncthreads();
      { // stage A rows [32c,32c+32) x 128: 4096 floats, 1 float4/thread
        ((float4*)smem)[t] = ((const float4*)(Ab + c*32*Nn))[t];
      }
      __syncthreads();
      #pragma unroll 4
      for (int m=0;m<32;m++) {
        const float4 ri = *(const float4*)&smem[m*Nn + 4*ar];
        const float4 rj = *(const float4*)&smem[m*Nn + 4*bc];
        const float iv[4] = {ri.x,ri.y,ri.z,ri.w};
        const float jv[4] = {rj.x,rj.y,rj.z,rj.w};
        #pragma unroll
        for (int a=0;a<4;a++)
          #pragma unroll
          for (int v=0;v<4;v++) acc[a][v] += iv[a]*jv[v];
      }
    }
    __syncthreads();
    #pragma unroll
    for (int a=0;a<4;a++) {
      const int i = 4*ar + a;
      const float4 p = *(const float4*)&Pb[i*Nn + 4*bc];
      float4 o;
      o.x = p.x + RHO_*acc[a][0] + ((i==4*bc+0)?SIGMA_:0.f);
      o.y = p.y + RHO_*acc[a][1] + ((i==4*bc+1)?SIGMA_:0.f);
      o.z = p.z + RHO_*acc[a][2] + ((i==4*bc+2)?SIGMA_:0.f);
      o.w = p.w + RHO_*acc[a][3] + ((i==4*bc+3)?SIGMA_:0.f);
      *(float4*)&smem[i*Nn + 4*bc] = o;
    }
    __syncthreads();
  }

  //---- Phase B: S <- S^-1 Gauss-Jordan, 8 lanes/row, 1 barrier/step ----
  {
    const int irow = t >> 3;            // 0..127
    const int oct  = t & 7;             // col 16-chunk
    float rr[16];
    #pragma unroll
    for (int j4=0;j4<4;j4++)
      *(float4*)&rr[4*j4] = *(const float4*)&smem[irow*Nn + 16*oct + 4*j4];
    __syncthreads();                    // all rr loaded before bufs alias smem
    float* buf0 = smem;                 // [160]
    float* buf1 = smem + 160;           // [160]
    gj_block8<0>(rr, buf0, buf1, irow, oct);
    gj_block8<1>(rr, buf0, buf1, irow, oct);
    gj_block8<2>(rr, buf0, buf1, irow, oct);
    gj_block8<3>(rr, buf0, buf1, irow, oct);
    gj_block8<4>(rr, buf0, buf1, irow, oct);
    gj_block8<5>(rr, buf0, buf1, irow, oct);
    gj_block8<6>(rr, buf0, buf1, irow, oct);
    gj_block8<7>(rr, buf0, buf1, irow, oct);
    __syncthreads();                    // last step's reads done
    #pragma unroll
    for (int j4=0;j4<4;j4++)
      *(float4*)&smem[irow*Nn + 16*oct + 4*j4] = *(const float4*)&rr[4*j4];
  }
  __syncthreads();

  //---- Phase C: Wt = A*Minv -> wsWt; c = Minv q -> wsC ----
  {
    const int rg = t >> 4, cg = t & 15;
    float acc[3][8];
    #pragma unroll
    for (int a=0;a<3;a++)
      #pragma unroll
      for (int p=0;p<8;p++) acc[a][p]=0.f;

    for (int k4=0;k4<32;k4++) {
      v4f av[3];
      av[0] = *(const v4f*)&Ab[(rg      )*Nn + 4*k4];
      av[1] = *(const v4f*)&Ab[(rg +  64)*Nn + 4*k4];
      av[2] = *(const v4f*)&Ab[(rg + 128)*Nn + 4*k4];
      #pragma unroll
      for (int q=0;q<4;q++) {
        const int m = 4*k4 + q;
        const v4f w0 = *(const v4f*)&smem[m*Nn + 8*cg];
        const v4f w1 = *(const v4f*)&smem[m*Nn + 8*cg + 4];
        #pragma unroll
        for (int a=0;a<3;a++) {
          const float amq = (q==0)?av[a].x : (q==1)?av[a].y : (q==2)?av[a].z : av[a].w;
          acc[a][0] += amq*w0.x; acc[a][1] += amq*w0.y;
          acc[a][2] += amq*w0.z; acc[a][3] += amq*w0.w;
          acc[a][4] += amq*w1.x; acc[a][5] += amq*w1.y;
          acc[a][6] += amq*w1.z; acc[a][7] += amq*w1.w;
        }
      }
    }
    float* wb = wsWt + (size_t)b*Mm*Nn;
    #pragma unroll
    for (int a=0;a<3;a++) {
      const int j = rg + 64*a;
      *(float4*)&wb[j*Nn + 8*cg]     = make_float4(acc[a][0],acc[a][1],acc[a][2],acc[a][3]);
      *(float4*)&wb[j*Nn + 8*cg + 4] = make_float4(acc[a][4],acc[a][5],acc[a][6],acc[a][7]);
    }
  }
  // c[r] = sum_k Minv[k][r] q[k]  (Minv symmetric; lane-consecutive LDS reads)
  if (t < Nn) {
    float cc = 0.f;
    #pragma unroll 4
    for (int k=0;k<Nn;k++) cc += smem[k*Nn + t] * qb[k];
    wsC[(size_t)b*Nn + t] = cc;
  }
}

//======================= Kernel 2: V blobs (1024 blocks x 256 thr) =================
// Block = (b = bid>>2, v = bid&3); thread tl serves loop-thread t = 256v+tl:
// ig = 16v + (tl>>4), cg = tl&15.  blob[t][a*12+jj] = V[ig+64a][cg+16jj]
//   = dot(A_{ig+64a}, Wt_{cg+16jj}).  Tiles: A 48x32 + Wt 192x32, stride 36.
__global__ void __launch_bounds__(256, 2)
vcompute_kernel(const float* __restrict__ Ag, const float* __restrict__ wsWt,
                float* __restrict__ wsV)
{
  __shared__ float At[48*36];     //  6.75 KiB
  __shared__ float Wtt[192*36];   // 27 KiB
  const int tl = threadIdx.x;
  const int b  = blockIdx.x >> 2, v = blockIdx.x & 3;
  const int il = tl >> 4, cg = tl & 15;
  const float* __restrict__ Ab = Ag   + (size_t)b*Mm*Nn;
  const float* __restrict__ Wb = wsWt + (size_t)b*Mm*Nn;

  float acc[3][12];
  #pragma unroll
  for (int a=0;a<3;a++)
    #pragma unroll
    for (int jj=0;jj<12;jj++) acc[a][jj]=0.f;

  for (int kc=0;kc<4;kc++) {
    __syncthreads();
    { // A-tile: 384 float4 (tile row r = a*16+rl <-> global row 16v+rl+64a)
      int x = tl;
      #pragma unroll
      for (int i=0;i<2;i++) {
        if (x < 384) {
          const int row = x>>3, c4 = x&7;
          const int grow = 16*v + (row&15) + 64*(row>>4);
          *(float4*)&At[36*row+4*c4] = *(const float4*)&Ab[grow*Nn + 32*kc + 4*c4];
        }
        x += 256;
      }
    }
    { // Wt-tile: 1536 float4
      #pragma unroll
      for (int i=0;i<6;i++) {
        const int x = tl + 256*i;
        const int row = x>>3, c4 = x&7;
        *(float4*)&Wtt[36*row+4*c4] = *(const float4*)&Wb[row*Nn + 32*kc + 4*c4];
      }
    }
    __syncthreads();
    #pragma unroll
    for (int m4=0;m4<8;m4++) {
      v4f av[3];
      av[0] = *(const v4f*)&At[36*(il     ) + 4*m4];
      av[1] = *(const v4f*)&At[36*(il + 16) + 4*m4];
      av[2] = *(const v4f*)&At[36*(il + 32) + 4*m4];
      #pragma unroll
      for (int jj=0;jj<12;jj++) {
        const v4f w = *(const v4f*)&Wtt[36*(cg+16*jj)+4*m4];
        acc[0][jj] += av[0].x*w.x + av[0].y*w.y + av[0].z*w.z + av[0].w*w.w;
        acc[1][jj] += av[1].x*w.x + av[1].y*w.y + av[1].z*w.z + av[1].w*w.w;
        acc[2][jj] += av[2].x*w.x + av[2].y*w.y + av[2].z*w.z + av[2].w*w.w;
      }
    }
  }

  float* blob = wsV + (size_t)(blockIdx.x*256 + tl)*36;
  #pragma unroll
  for (int a=0;a<3;a++)
    #pragma unroll
    for (int g=0;g<3;g++)
      *(float4*)&blob[a*12+4*g] =
        make_float4(acc[a][4*g],acc[a][4*g+1],acc[a][4*g+2],acc[a][4*g+3]);
}

//======================= Kernel 3: V-space ADMM loop (1024 thr) ====================
// R5-validated mapping/ITER. ig = t>>4, cg = t&15; rows {ig+64a}, cols
// {cg+16jj}; s transposed: s_j at slot (j&15)*12+(j>>4). Producers cg<3,
// pm = 64cg+ig. V from the per-thread blob (coalesced 144B). ~2.3KB LDS.
__global__ void __launch_bounds__(1024, 4)
loop_kernel(const float* __restrict__ Ag, const float* __restrict__ lg,
            const float* __restrict__ ug, const float* __restrict__ wsWt,
            const float* __restrict__ wsC, const float* __restrict__ wsV,
            float* __restrict__ outg)
{
  __shared__ float smem[576];    // sT0[192] | sT1[192] | sacc[192]
  const int t = threadIdx.x, b = blockIdx.x;
  const int ig = t >> 4, cg = t & 15;
  const float* __restrict__ Ab = Ag   + (size_t)b*Mm*Nn;
  const float* __restrict__ Wb = wsWt + (size_t)b*Mm*Nn;
  const float* __restrict__ cb = wsC  + (size_t)b*Nn;

  const int  pm  = 64*cg + ig;          // producer row (cg<3)
  const bool isp = (cg < 3);

  // ---- V rows from blob: 9 coalesced float4 loads ----
  float Vr[3][12];
  {
    const float* blob = wsV + (size_t)(b*1024 + t)*36;
    #pragma unroll
    for (int a=0;a<3;a++)
      #pragma unroll
      for (int g=0;g<3;g++) {
        const float4 tmp = *(const float4*)&blob[a*12+4*g];
        Vr[a][4*g]=tmp.x; Vr[a][4*g+1]=tmp.y; Vr[a][4*g+2]=tmp.z; Vr[a][4*g+3]=tmp.w;
      }
  }

  // ---- d = A_pm . c ; bounds (producers) ----
  float dreg = 0.f, lreg = 0.f, ureg = 0.f;
  if (isp) {
    lreg = lg[(size_t)b*Mm + pm];
    ureg = ug[(size_t)b*Mm + pm];
    const float4* ar = (const float4*)(Ab + pm*Nn);
    const float4* cr = (const float4*)cb;
    #pragma unroll 4
    for (int k4=0;k4<32;k4++) {
      const float4 av = ar[k4], cv = cr[k4];
      dreg += av.x*cv.x + av.y*cv.y + av.z*cv.z + av.w*cv.w;
    }
  }

  float* sT0  = smem;
  float* sT1  = smem + 192;
  float* sacc = smem + 384;
  if (t < Mm) sT0[t] = 0.f;
  __syncthreads();

  const int woff = (pm & 15)*12 + (pm >> 4);
  // state: p = (1-a)z + y/rho (0 at start), s, Sacc
  float sreg = 0.f, preg = 0.f, Sacc = 0.f;
  const float* sR0 = sT0 + 12*cg;
  const float* sR1 = sT1 + 12*cg;

#define ITER(RD, WR)                                                           \
  {                                                                            \
    const float4 sA = *(const float4*)(RD);                                    \
    const float4 sB = *(const float4*)((RD) + 4);                              \
    const float4 sC = *(const float4*)((RD) + 8);                              \
    float r0 = Vr[0][0]*sA.x + Vr[0][1]*sA.y + Vr[0][2]*sA.z + Vr[0][3]*sA.w   \
             + Vr[0][4]*sB.x + Vr[0][5]*sB.y + Vr[0][6]*sB.z + Vr[0][7]*sB.w   \
             + Vr[0][8]*sC.x + Vr[0][9]*sC.y + Vr[0][10]*sC.z + Vr[0][11]*sC.w;\
    float r1 = Vr[1][0]*sA.x + Vr[1][1]*sA.y + Vr[1][2]*sA.z + Vr[1][3]*sA.w   \
             + Vr[1][4]*sB.x + Vr[1][5]*sB.y + Vr[1][6]*sB.z + Vr[1][7]*sB.w   \
             + Vr[1][8]*sC.x + Vr[1][9]*sC.y + Vr[1][10]*sC.z + Vr[1][11]*sC.w;\
    float r2 = Vr[2][0]*sA.x + Vr[2][1]*sA.y + Vr[2][2]*sA.z + Vr[2][3]*sA.w   \
             + Vr[2][4]*sB.x + Vr[2][5]*sB.y + Vr[2][6]*sB.z + Vr[2][7]*sB.w   \
             + Vr[2][8]*sC.x + Vr[2][9]*sC.y + Vr[2][10]*sC.z + Vr[2][11]*sC.w;\
    r0 = red16(r0); r1 = red16(r1); r2 = red16(r2);                            \
    if (isp) {                                                                 \
      const float r  = (cg==0) ? r0 : ((cg==1) ? r1 : r2);                     \
      const float w  = r - dreg;                                               \
      const float v  = fmaf(ALPHA_, w, preg);                                  \
      const float z  = __builtin_amdgcn_fmed3f(v, lreg, ureg);                 \
      const float sn = RHO_ * fmaf(2.0f, z, -v);                               \
      (WR)[woff] = sn;                                                         \
      Sacc = (1.f-ALPHA_)*Sacc + ALPHA_*sreg;                                  \
      sreg = sn;                                                               \
      preg = fmaf(-ALPHA_, z, v);                                              \
    }                                                                          \
    __syncthreads();                                                           \
  }

  #pragma unroll 1
  for (int it2 = 0; it2 < NITERS_/2; it2++) {
    ITER(sR0, sT1)
    ITER(sR1, sT0)
  }
#undef ITER

  // ---- epilogue: x = Wt^T Sacc - c ----
  if (isp) sacc[pm] = Sacc;
  __syncthreads();
  if (t < Nn) {
    float acc = -cb[t];
    #pragma unroll 4
    for (int j=0;j<Mm;j++) acc += Wb[j*Nn + t] * sacc[j];
    outg[(size_t)b*Nn + t] = acc;
  }
}

extern "C" void kernel_launch(void* const* d_in, const int* in_sizes, int n_in,
                              void* d_out, int out_size, void* d_ws, size_t ws_size,
                              hipStream_t stream) {
  const float* P = (const float*)d_in[0];
  const float* q = (const float*)d_in[1];
  const float* A = (const float*)d_in[2];
  const float* l = (const float*)d_in[3];
  const float* u = (const float*)d_in[4];
  (void)in_sizes; (void)n_in; (void)out_size; (void)ws_size;
  float* wsWt = (float*)d_ws;                      // 256*192*128 fl = 25.2 MB
  float* wsC  = wsWt + (size_t)256*Mm*Nn;          // 256*128 fl
  float* wsV  = wsC  + (size_t)256*Nn;             // 256*1024*36 fl = 37.7 MB
  precompute_kernel<<<256, 1024, 0, stream>>>(P, q, A, wsWt, wsC);
  vcompute_kernel<<<1024, 256, 0, stream>>>(A, wsWt, wsV);
  loop_kernel<<<256, 1024, 0, stream>>>(A, l, u, wsWt, wsC, wsV, (float*)d_out);
}